// Round 3
// baseline (251.052 us; speedup 1.0000x reference)
//
#include <hip/hip_runtime.h>
#include <hip/hip_bf16.h>

typedef __bf16 bf16x8 __attribute__((ext_vector_type(8)));
typedef __bf16 bf16x4 __attribute__((ext_vector_type(4)));
typedef float  f32x4  __attribute__((ext_vector_type(4)));

#define H 768
#define LSEQ 2048
#define BATCH 32
#define MROWS (BATCH*LSEQ)   /* 65536 */
#define NT 3                 /* 768/256 n-tiles */
#define W2S 2304             /* W2 row stride (3H) */

__device__ __forceinline__ void gload_lds16(const void* g, void* l){
  __builtin_amdgcn_global_load_lds((const __attribute__((address_space(1))) void*)g,
                                   (__attribute__((address_space(3))) void*)l, 16, 0, 0);
}

// ---- convert W2c = W2[:, 2H:3H] to bf16 (row-major [g][h], h contiguous) ----
__global__ void w2c_cvt_k(const float* __restrict__ W2, __bf16* __restrict__ w2cb){
  int i4 = blockIdx.x*256 + threadIdx.x;     // 147456 float4s total
  int g  = i4 / 192;
  int hc = (i4 % 192) * 4;
  f32x4 v = *(const f32x4*)(W2 + (size_t)g*W2S + 1536 + hc);
  bf16x4 o; o[0]=(__bf16)v[0]; o[1]=(__bf16)v[1]; o[2]=(__bf16)v[2]; o[3]=(__bf16)v[3];
  *(bf16x4*)(w2cb + (size_t)g*H + hc) = o;
}

// ---- bias_bh[b][g] = in1[b]·W2a[g] + in2[b]·W2b[g] + b2[g] ----
__global__ void bias_k(const float* __restrict__ in1, const float* __restrict__ in2,
                       const float* __restrict__ W2, const float* __restrict__ b2,
                       float* __restrict__ bias){
  int b = blockIdx.y;
  int g = blockIdx.x*64 + (threadIdx.x & 63);
  int q = threadIdx.x >> 6;                  // h-quarter
  const float* wa = W2 + (size_t)g*W2S + q*192;
  const float* wb = wa + H;
  const float* x1 = in1 + b*H + q*192;
  const float* x2 = in2 + b*H + q*192;
  float acc = 0.f;
  #pragma unroll 8
  for (int h=0; h<192; h+=4){
    f32x4 a4 = *(const f32x4*)(wa+h);
    f32x4 c4 = *(const f32x4*)(x1+h);
    f32x4 b4 = *(const f32x4*)(wb+h);
    f32x4 d4 = *(const f32x4*)(x2+h);
    acc += a4[0]*c4[0]+a4[1]*c4[1]+a4[2]*c4[2]+a4[3]*c4[3];
    acc += b4[0]*d4[0]+b4[1]*d4[1]+b4[2]*d4[2]+b4[3]*d4[3];
  }
  __shared__ float sm[4][64];
  sm[q][threadIdx.x&63] = acc;
  __syncthreads();
  if (q==0){
    float r = sm[0][threadIdx.x]+sm[1][threadIdx.x]+sm[2][threadIdx.x]+sm[3][threadIdx.x] + b2[g];
    bias[(size_t)b*H + g] = r;
  }
}

// ---- fused: S = text·W2c^T (bf16 MFMA), att_part = sum_g tanh(S+bias)·W1 ----
// 128x256 tile, BK=32, 4 waves (2x2), wave-tile 64x128.
// LDS rows are 64 B (4 x 16B k-granules); granule XOR-swizzle g ^= (row>>1)&3
// kills the 8-way bank aliasing of 16-consecutive-row b128 fragment reads.
// A: reg-staged f32->bf16 with swizzled ds_write (write-side swizzle).
// B: global_load_lds with PRE-SWIZZLED global source, linear LDS dest (rule 21).
// XCD-chunked block swizzle keeps each m-tile's 3 n-siblings on one XCD L2.
__global__ __launch_bounds__(256) void fused_gemm_att_k(
    const float* __restrict__ text, const __bf16* __restrict__ w2cb,
    const float* __restrict__ bias, const float* __restrict__ W1,
    float* __restrict__ attp)
{
  __shared__ __align__(16) __bf16 a_lds[2][128*32];  // 16 KiB
  __shared__ __align__(16) __bf16 b_lds[2][256*32];  // 32 KiB
  __shared__ float att_lds[2][128];

  int bid = blockIdx.x;                 // 1536 = 512 m-tiles * 3 n-tiles
  int lin = (bid & 7)*192 + (bid >> 3); // bijective XCD chunking (1536 % 8 == 0)
  int mt  = lin / 3;
  int nt  = lin % 3;
  int b   = mt >> 4;                    // 128 rows/tile, 2048 rows/batch
  int m0  = mt << 7;
  int t = threadIdx.x, lane = t & 63, wid = t >> 6;
  int wm = wid >> 1, wn = wid & 1;

  const float*  atile = text + (size_t)m0*H;
  const __bf16* btile = w2cb + (size_t)(nt*256)*H;

  f32x4 acc[4][8];
  #pragma unroll
  for (int mi=0;mi<4;++mi)
    #pragma unroll
    for (int ni=0;ni<8;++ni) acc[mi][ni] = (f32x4){0.f,0.f,0.f,0.f};

  int ar = t>>3, ac = (t&7)*4;          // A stage: row base, f32 col
  int ag = (t&7)>>1, ah = t&1;          // k-granule (16B bf16), half (8B)
  f32x4 aReg[4];

  auto loadA = [&](int kk){
    #pragma unroll
    for (int j=0;j<4;++j)
      aReg[j] = *(const f32x4*)(atile + (size_t)(ar + j*32)*H + kk*32 + ac);
  };
  auto writeA = [&](int bf){
    #pragma unroll
    for (int j=0;j<4;++j){
      int row = ar + j*32;
      int gc  = ag ^ ((row>>1)&3);      // swizzled granule column
      bf16x4 o; o[0]=(__bf16)aReg[j][0]; o[1]=(__bf16)aReg[j][1];
                o[2]=(__bf16)aReg[j][2]; o[3]=(__bf16)aReg[j][3];
      *(bf16x4*)&a_lds[bf][row*32 + gc*8 + ah*4] = o;
    }
  };
  auto stageB = [&](int bf, int kk){
    #pragma unroll
    for (int j=0;j<4;++j){
      int slot = wid*4 + j;                        // 16 slots of 1 KiB
      int n  = slot*16 + (lane>>2);
      int gs = (lane&3) ^ ((lane>>3)&3);           // pre-swizzled source granule
      gload_lds16(btile + (size_t)n*H + kk*32 + gs*8, &b_lds[bf][slot*512]);
    }
  };
  auto compute = [&](int bf){
    bf16x8 af[4];
    #pragma unroll
    for (int mi=0;mi<4;++mi){
      int row = wm*64 + mi*16 + (lane&15);
      int rc  = (lane>>4) ^ ((row>>1)&3);
      af[mi] = *(const bf16x8*)&a_lds[bf][row*32 + rc*8];
    }
    #pragma unroll
    for (int ni=0;ni<8;++ni){
      int n  = wn*128 + ni*16 + (lane&15);
      int rc = (lane>>4) ^ ((n>>1)&3);
      bf16x8 bq = *(const bf16x8*)&b_lds[bf][n*32 + rc*8];
      #pragma unroll
      for (int mi=0;mi<4;++mi)
        acc[mi][ni] = __builtin_amdgcn_mfma_f32_16x16x32_bf16(af[mi], bq, acc[mi][ni], 0,0,0);
    }
  };

  // prologue: buf0 <- step 0; preload A regs for step 1
  loadA(0);
  writeA(0);
  stageB(0, 0);
  loadA(1);
  __syncthreads();

  #pragma unroll 2
  for (int kk=0; kk<24; ++kk){
    int nxt = (kk+1)&1;
    if (kk+1 < 24){
      stageB(nxt, kk+1);      // async into other buffer, drained by barrier below
      writeA(nxt);            // regs loaded a full phase ago
      if (kk+2 < 24) loadA(kk+2);
    }
    compute(kk&1);
    __syncthreads();
  }

  // ---- epilogue: lane n-col = nt*256 + wn*128 + ni*16 + (lane&15)
  float bb[8], ww[8];
  int gb = nt*256 + wn*128 + (lane&15);
  #pragma unroll
  for (int ni=0;ni<8;++ni){ bb[ni]=bias[(size_t)b*H + gb + ni*16]; ww[ni]=W1[gb + ni*16]; }

  float av[16];
  #pragma unroll
  for (int mi=0;mi<4;++mi)
    #pragma unroll
    for (int r=0;r<4;++r){
      float s = 0.f;
      #pragma unroll
      for (int ni=0;ni<8;++ni){
        float x = acc[mi][ni][r] + bb[ni];
        float e = __expf(2.0f*x);            // tanh(x) = (e^2x-1)/(e^2x+1)
        s += ww[ni] * ((e-1.0f)/(e+1.0f));
      }
      av[mi*4+r] = s;
    }
  #pragma unroll
  for (int off=1; off<16; off<<=1)
    #pragma unroll
    for (int i=0;i<16;++i) av[i] += __shfl_xor(av[i], off);

  if ((lane&15)==0){
    int mg = (lane>>4)*4;   // acc rows live in lane>>4
    #pragma unroll
    for (int mi=0;mi<4;++mi)
      #pragma unroll
      for (int r=0;r<4;++r)
        att_lds[wn][wm*64 + mi*16 + mg + r] = av[mi*4+r];
  }
  __syncthreads();
  if (t < 128) attp[(size_t)nt*MROWS + m0 + t] = att_lds[0][t] + att_lds[1][t];
}

// ---- softmax over L per batch row (sums the 3 n-tile partials) ----
__global__ void softmax_k(const float* __restrict__ attp, const float* __restrict__ tmask,
                          const float* __restrict__ b1, float* __restrict__ att){
  int b = blockIdx.x, t = threadIdx.x;
  int lane = t & 63, wv = t >> 6;
  __shared__ float sl[LSEQ];
  __shared__ float red[4];
  float b1v = b1[0];
  float lmax = -3.0e38f;
  for (int i=t; i<LSEQ; i+=256){
    float v = b1v;
    #pragma unroll
    for (int p=0;p<NT;++p) v += attp[(size_t)p*MROWS + b*LSEQ + i];
    v += (1.0f - tmask[b*LSEQ+i]) * -1.0e20f;
    sl[i] = v;
    lmax = fmaxf(lmax, v);
  }
  #pragma unroll
  for (int off=32; off>=1; off>>=1) lmax = fmaxf(lmax, __shfl_xor(lmax, off));
  if (lane==0) red[wv] = lmax;
  __syncthreads();
  float mx = fmaxf(fmaxf(red[0],red[1]), fmaxf(red[2],red[3]));
  __syncthreads();
  float lsum = 0.f;
  for (int i=t; i<LSEQ; i+=256){
    float e = __expf(sl[i]-mx);
    sl[i] = e;
    lsum += e;
  }
  #pragma unroll
  for (int off=32; off>=1; off>>=1) lsum += __shfl_xor(lsum, off);
  if (lane==0) red[wv] = lsum;
  __syncthreads();
  float inv = 1.0f/(red[0]+red[1]+red[2]+red[3]);
  for (int i=t; i<LSEQ; i+=256) att[(size_t)b*LSEQ+i] = sl[i]*inv;
}

// ---- context partials: 64-row chunks, block=192 threads (one float4 per thread) ----
__global__ void ctxpart_k(const float* __restrict__ text, const float* __restrict__ att,
                          float* __restrict__ ctxp){
  int chunk = blockIdx.x, b = blockIdx.y, t = threadIdx.x;
  const float* tp = text + ((size_t)(b*LSEQ + chunk*64))*H + 4*t;
  const float* ap = att + (size_t)b*LSEQ + chunk*64;
  f32x4 acc = {0.f,0.f,0.f,0.f};
  #pragma unroll 4
  for (int l=0;l<64;++l){
    float a = ap[l];
    f32x4 v = *(const f32x4*)(tp + (size_t)l*H);
    acc[0] += a*v[0]; acc[1] += a*v[1]; acc[2] += a*v[2]; acc[3] += a*v[3];
  }
  *(f32x4*)(ctxp + ((size_t)(b*32+chunk))*H + 4*t) = acc;
}

__global__ void ctxred_k(const float* __restrict__ ctxp, float* __restrict__ out){
  int b = blockIdx.x, h = threadIdx.x;   // block 768
  float s = 0.f;
  #pragma unroll 8
  for (int c=0;c<32;++c) s += ctxp[((size_t)(b*32+c))*H + h];
  out[(size_t)b*H + h] = s;
}

extern "C" void kernel_launch(void* const* d_in, const int* in_sizes, int n_in,
                              void* d_out, int out_size, void* d_ws, size_t ws_size,
                              hipStream_t stream){
  (void)in_sizes; (void)n_in; (void)out_size; (void)ws_size;
  const float* in1   = (const float*)d_in[0];
  const float* in2   = (const float*)d_in[1];
  const float* text  = (const float*)d_in[2];
  const float* tmask = (const float*)d_in[3];
  const float* W2    = (const float*)d_in[4];
  const float* b2    = (const float*)d_in[5];
  const float* W1    = (const float*)d_in[6];
  const float* b1    = (const float*)d_in[7];
  float* out = (float*)d_out;              // [0,24576): context, [24576,90112): att
  char*  ws  = (char*)d_ws;
  // ws layout (bytes): w2c bf16 1179648 | bias 98304 | attp 786432 | ctxp 3145728
  __bf16* w2cb = (__bf16*)(ws);
  float* biasb = (float*)(ws + 1179648);
  float* attp  = (float*)(ws + 1277952);
  float* ctxp  = (float*)(ws + 2850816);
  float* att_out = out + BATCH*H;

  w2c_cvt_k      <<<dim3(576),   dim3(256), 0, stream>>>(W2, w2cb);
  bias_k         <<<dim3(12,32), dim3(256), 0, stream>>>(in1, in2, W2, b2, biasb);
  fused_gemm_att_k<<<dim3(1536), dim3(256), 0, stream>>>(text, w2cb, biasb, W1, attp);
  softmax_k      <<<dim3(32),    dim3(256), 0, stream>>>(attp, tmask, b1, att_out);
  ctxpart_k      <<<dim3(32,32), dim3(192), 0, stream>>>(text, att_out, ctxp);
  ctxred_k       <<<dim3(32),    dim3(768), 0, stream>>>(ctxp, out);
}

// Round 4
// 182.041 us; speedup vs baseline: 1.3791x; 1.3791x over previous
//
#include <hip/hip_runtime.h>
#include <hip/hip_bf16.h>

typedef __bf16 bf16x8 __attribute__((ext_vector_type(8)));
typedef __bf16 bf16x4 __attribute__((ext_vector_type(4)));
typedef float  f32x4  __attribute__((ext_vector_type(4)));

#define H 768
#define LSEQ 2048
#define BATCH 32
#define MROWS (BATCH*LSEQ)   /* 65536 */
#define NT 3                 /* 768/256 n-tiles */
#define W2S 2304             /* W2 row stride (3H) */

__device__ __forceinline__ void gload_lds16(const void* g, void* l){
  __builtin_amdgcn_global_load_lds((const __attribute__((address_space(1))) void*)g,
                                   (__attribute__((address_space(3))) void*)l, 16, 0, 0);
}

// ---- convert W2c = W2[:, 2H:3H] to bf16 (row-major [g][h], h contiguous) ----
__global__ void w2c_cvt_k(const float* __restrict__ W2, __bf16* __restrict__ w2cb){
  int i4 = blockIdx.x*256 + threadIdx.x;     // 147456 float4s total
  int g  = i4 / 192;
  int hc = (i4 % 192) * 4;
  f32x4 v = *(const f32x4*)(W2 + (size_t)g*W2S + 1536 + hc);
  bf16x4 o; o[0]=(__bf16)v[0]; o[1]=(__bf16)v[1]; o[2]=(__bf16)v[2]; o[3]=(__bf16)v[3];
  *(bf16x4*)(w2cb + (size_t)g*H + hc) = o;
}

// ---- bias_bh[b][g] = in1[b]·W2a[g] + in2[b]·W2b[g] + b2[g] ----
__global__ void bias_k(const float* __restrict__ in1, const float* __restrict__ in2,
                       const float* __restrict__ W2, const float* __restrict__ b2,
                       float* __restrict__ bias){
  int b = blockIdx.y;
  int g = blockIdx.x*64 + (threadIdx.x & 63);
  int q = threadIdx.x >> 6;                  // h-quarter
  const float* wa = W2 + (size_t)g*W2S + q*192;
  const float* wb = wa + H;
  const float* x1 = in1 + b*H + q*192;
  const float* x2 = in2 + b*H + q*192;
  float acc = 0.f;
  #pragma unroll 8
  for (int h=0; h<192; h+=4){
    f32x4 a4 = *(const f32x4*)(wa+h);
    f32x4 c4 = *(const f32x4*)(x1+h);
    f32x4 b4 = *(const f32x4*)(wb+h);
    f32x4 d4 = *(const f32x4*)(x2+h);
    acc += a4[0]*c4[0]+a4[1]*c4[1]+a4[2]*c4[2]+a4[3]*c4[3];
    acc += b4[0]*d4[0]+b4[1]*d4[1]+b4[2]*d4[2]+b4[3]*d4[3];
  }
  __shared__ float sm[4][64];
  sm[q][threadIdx.x&63] = acc;
  __syncthreads();
  if (q==0){
    float r = sm[0][threadIdx.x]+sm[1][threadIdx.x]+sm[2][threadIdx.x]+sm[3][threadIdx.x] + b2[g];
    bias[(size_t)b*H + g] = r;
  }
}

// ---- fused: S = text·W2c^T (bf16 MFMA), att_part = sum_g tanh(S+bias)·W1 ----
// 128x256 tile, BK=32, 4 waves (2x2), wave-tile 64x128.
// Granule XOR-swizzle (g ^= (row>>1)&3) on both LDS tiles -> 0 bank conflicts (R3-verified).
// A: reg-staged f32->bf16, swizzled ds_write. B: gload_lds, pre-swizzled source.
// T4 counted-vmcnt barrier: per-step wait is vmcnt(4) -- drains only stageB's 4
// gload_lds (FIFO-oldest), leaving loadA's 4 HBM loads in flight a full extra step.
__global__ __launch_bounds__(256,2) void fused_gemm_att_k(
    const float* __restrict__ text, const __bf16* __restrict__ w2cb,
    const float* __restrict__ bias, const float* __restrict__ W1,
    float* __restrict__ attp)
{
  __shared__ __align__(16) __bf16 a_lds[2][128*32];  // 16 KiB
  __shared__ __align__(16) __bf16 b_lds[2][256*32];  // 32 KiB
  __shared__ float att_lds[2][128];

  int bid = blockIdx.x;                 // 1536 = 512 m-tiles * 3 n-tiles
  int lin = (bid & 7)*192 + (bid >> 3); // bijective XCD chunking (1536 % 8 == 0)
  int mt  = lin / 3;
  int nt  = lin % 3;
  int b   = mt >> 4;                    // 128 rows/tile, 2048 rows/batch
  int m0  = mt << 7;
  int t = threadIdx.x, lane = t & 63, wid = t >> 6;
  int wm = wid >> 1, wn = wid & 1;

  const float*  atile = text + (size_t)m0*H;
  const __bf16* btile = w2cb + (size_t)(nt*256)*H;

  f32x4 acc[4][8];
  #pragma unroll
  for (int mi=0;mi<4;++mi)
    #pragma unroll
    for (int ni=0;ni<8;++ni) acc[mi][ni] = (f32x4){0.f,0.f,0.f,0.f};

  int ar = t>>3, ac = (t&7)*4;          // A stage: row base, f32 col
  int ag = (t&7)>>1, ah = t&1;          // k-granule (16B bf16), half (8B)
  f32x4 aReg[4];

  auto loadA = [&](int kk){
    #pragma unroll
    for (int j=0;j<4;++j)
      aReg[j] = *(const f32x4*)(atile + (size_t)(ar + j*32)*H + kk*32 + ac);
  };
  auto writeA = [&](int bf){
    #pragma unroll
    for (int j=0;j<4;++j){
      int row = ar + j*32;
      int gc  = ag ^ ((row>>1)&3);      // swizzled granule column
      bf16x4 o; o[0]=(__bf16)aReg[j][0]; o[1]=(__bf16)aReg[j][1];
                o[2]=(__bf16)aReg[j][2]; o[3]=(__bf16)aReg[j][3];
      *(bf16x4*)&a_lds[bf][row*32 + gc*8 + ah*4] = o;
    }
  };
  auto stageB = [&](int bf, int kk){
    #pragma unroll
    for (int j=0;j<4;++j){
      int slot = wid*4 + j;                        // 16 slots of 1 KiB
      int n  = slot*16 + (lane>>2);
      int gs = (lane&3) ^ ((lane>>3)&3);           // pre-swizzled source granule
      gload_lds16(btile + (size_t)n*H + kk*32 + gs*8, &b_lds[bf][slot*512]);
    }
  };
  auto compute = [&](int bf){
    bf16x8 af[4];
    #pragma unroll
    for (int mi=0;mi<4;++mi){
      int row = wm*64 + mi*16 + (lane&15);
      int rc  = (lane>>4) ^ ((row>>1)&3);
      af[mi] = *(const bf16x8*)&a_lds[bf][row*32 + rc*8];
    }
    #pragma unroll
    for (int ni=0;ni<8;++ni){
      int n  = wn*128 + ni*16 + (lane&15);
      int rc = (lane>>4) ^ ((n>>1)&3);
      bf16x8 bq = *(const bf16x8*)&b_lds[bf][n*32 + rc*8];
      #pragma unroll
      for (int mi=0;mi<4;++mi)
        acc[mi][ni] = __builtin_amdgcn_mfma_f32_16x16x32_bf16(af[mi], bq, acc[mi][ni], 0,0,0);
    }
  };

  // prologue: buf0 <- step 0; preload A regs for step 1
  loadA(0);
  writeA(0);
  stageB(0, 0);
  loadA(1);
  __syncthreads();      // full drain once (prologue only)

  // main loop kk=0..21: stageB(kk+1) and loadA(kk+2) always valid.
  // Per-iter vmem FIFO: [stageB:4][loadA:4] -> barrier waits vmcnt(4) = stageB only.
  #pragma unroll 2
  for (int kk=0; kk<22; ++kk){
    int cur = kk&1, nxt = cur^1;
    stageB(nxt, kk+1);        // 4 gload_lds (oldest)
    writeA(nxt);              // aReg = A[kk+1], loaded last iter (compiler waits its vmcnt)
    loadA(kk+2);              // 4 HBM loads -- NOT drained by this step's barrier
    compute(cur);
    asm volatile("s_waitcnt vmcnt(4) lgkmcnt(0)" ::: "memory");
    __builtin_amdgcn_sched_barrier(0);
    __builtin_amdgcn_s_barrier();
    __builtin_amdgcn_sched_barrier(0);
  }
  // kk=22: stage step 23, no loadA left; outstanding vmem = stageB only -> vmcnt(0)
  {
    stageB(1, 23);
    writeA(1);                // aReg = A[23] (loaded at kk=21)
    compute(0);
    asm volatile("s_waitcnt vmcnt(0) lgkmcnt(0)" ::: "memory");
    __builtin_amdgcn_sched_barrier(0);
    __builtin_amdgcn_s_barrier();
    __builtin_amdgcn_sched_barrier(0);
  }
  // kk=23: final compute, no staging
  compute(1);

  // ---- epilogue: lane n-col = nt*256 + wn*128 + ni*16 + (lane&15)
  float bb[8], ww[8];
  int gb = nt*256 + wn*128 + (lane&15);
  #pragma unroll
  for (int ni=0;ni<8;++ni){ bb[ni]=bias[(size_t)b*H + gb + ni*16]; ww[ni]=W1[gb + ni*16]; }

  float av[16];
  #pragma unroll
  for (int mi=0;mi<4;++mi)
    #pragma unroll
    for (int r=0;r<4;++r){
      float s = 0.f;
      #pragma unroll
      for (int ni=0;ni<8;++ni){
        float x = acc[mi][ni][r] + bb[ni];
        float e = __expf(2.0f*x);            // tanh(x) = (e^2x-1)/(e^2x+1)
        s += ww[ni] * ((e-1.0f)*__builtin_amdgcn_rcpf(e+1.0f));
      }
      av[mi*4+r] = s;
    }
  #pragma unroll
  for (int off=1; off<16; off<<=1)
    #pragma unroll
    for (int i=0;i<16;++i) av[i] += __shfl_xor(av[i], off);

  if ((lane&15)==0){
    int mg = (lane>>4)*4;   // acc rows live in lane>>4
    #pragma unroll
    for (int mi=0;mi<4;++mi)
      #pragma unroll
      for (int r=0;r<4;++r)
        att_lds[wn][wm*64 + mi*16 + mg + r] = av[mi*4+r];
  }
  __syncthreads();
  if (t < 128) attp[(size_t)nt*MROWS + m0 + t] = att_lds[0][t] + att_lds[1][t];
}

// ---- softmax over L per batch row (sums the 3 n-tile partials) ----
__global__ void softmax_k(const float* __restrict__ attp, const float* __restrict__ tmask,
                          const float* __restrict__ b1, float* __restrict__ att){
  int b = blockIdx.x, t = threadIdx.x;
  int lane = t & 63, wv = t >> 6;
  __shared__ float sl[LSEQ];
  __shared__ float red[4];
  float b1v = b1[0];
  float lmax = -3.0e38f;
  for (int i=t; i<LSEQ; i+=256){
    float v = b1v;
    #pragma unroll
    for (int p=0;p<NT;++p) v += attp[(size_t)p*MROWS + b*LSEQ + i];
    v += (1.0f - tmask[b*LSEQ+i]) * -1.0e20f;
    sl[i] = v;
    lmax = fmaxf(lmax, v);
  }
  #pragma unroll
  for (int off=32; off>=1; off>>=1) lmax = fmaxf(lmax, __shfl_xor(lmax, off));
  if (lane==0) red[wv] = lmax;
  __syncthreads();
  float mx = fmaxf(fmaxf(red[0],red[1]), fmaxf(red[2],red[3]));
  __syncthreads();
  float lsum = 0.f;
  for (int i=t; i<LSEQ; i+=256){
    float e = __expf(sl[i]-mx);
    sl[i] = e;
    lsum += e;
  }
  #pragma unroll
  for (int off=32; off>=1; off>>=1) lsum += __shfl_xor(lsum, off);
  if (lane==0) red[wv] = lsum;
  __syncthreads();
  float inv = 1.0f/(red[0]+red[1]+red[2]+red[3]);
  for (int i=t; i<LSEQ; i+=256) att[(size_t)b*LSEQ+i] = sl[i]*inv;
}

// ---- context partials: 64-row chunks, block=192 threads (one float4 per thread) ----
__global__ void ctxpart_k(const float* __restrict__ text, const float* __restrict__ att,
                          float* __restrict__ ctxp){
  int chunk = blockIdx.x, b = blockIdx.y, t = threadIdx.x;
  const float* tp = text + ((size_t)(b*LSEQ + chunk*64))*H + 4*t;
  const float* ap = att + (size_t)b*LSEQ + chunk*64;
  f32x4 acc = {0.f,0.f,0.f,0.f};
  #pragma unroll 4
  for (int l=0;l<64;++l){
    float a = ap[l];
    f32x4 v = *(const f32x4*)(tp + (size_t)l*H);
    acc[0] += a*v[0]; acc[1] += a*v[1]; acc[2] += a*v[2]; acc[3] += a*v[3];
  }
  *(f32x4*)(ctxp + ((size_t)(b*32+chunk))*H + 4*t) = acc;
}

__global__ void ctxred_k(const float* __restrict__ ctxp, float* __restrict__ out){
  int b = blockIdx.x, h = threadIdx.x;   // block 768
  float s = 0.f;
  #pragma unroll 8
  for (int c=0;c<32;++c) s += ctxp[((size_t)(b*32+c))*H + h];
  out[(size_t)b*H + h] = s;
}

extern "C" void kernel_launch(void* const* d_in, const int* in_sizes, int n_in,
                              void* d_out, int out_size, void* d_ws, size_t ws_size,
                              hipStream_t stream){
  (void)in_sizes; (void)n_in; (void)out_size; (void)ws_size;
  const float* in1   = (const float*)d_in[0];
  const float* in2   = (const float*)d_in[1];
  const float* text  = (const float*)d_in[2];
  const float* tmask = (const float*)d_in[3];
  const float* W2    = (const float*)d_in[4];
  const float* b2    = (const float*)d_in[5];
  const float* W1    = (const float*)d_in[6];
  const float* b1    = (const float*)d_in[7];
  float* out = (float*)d_out;              // [0,24576): context, [24576,90112): att
  char*  ws  = (char*)d_ws;
  // ws layout (bytes): w2c bf16 1179648 | bias 98304 | attp 786432 | ctxp 3145728
  __bf16* w2cb = (__bf16*)(ws);
  float* biasb = (float*)(ws + 1179648);
  float* attp  = (float*)(ws + 1277952);
  float* ctxp  = (float*)(ws + 2850816);
  float* att_out = out + BATCH*H;

  w2c_cvt_k      <<<dim3(576),   dim3(256), 0, stream>>>(W2, w2cb);
  bias_k         <<<dim3(12,32), dim3(256), 0, stream>>>(in1, in2, W2, b2, biasb);
  fused_gemm_att_k<<<dim3(1536), dim3(256), 0, stream>>>(text, w2cb, biasb, W1, attp);
  softmax_k      <<<dim3(32),    dim3(256), 0, stream>>>(attp, tmask, b1, att_out);
  ctxpart_k      <<<dim3(32,32), dim3(192), 0, stream>>>(text, att_out, ctxp);
  ctxred_k       <<<dim3(32),    dim3(768), 0, stream>>>(ctxp, out);
}